// Round 1
// baseline (1961.746 us; speedup 1.0000x reference)
//
#include <hip/hip_runtime.h>
#include <hip/hip_bf16.h>
#include <math.h>

#define G 64
#define NNODE 256      // nodes per graph (= O)
#define D_IN 128
#define HDIM 64
#define HEADS 4
#define E_PER 8192
#define NUM_NODES (G * NNODE)
#define E_TOTAL (G * E_PER)
#define BN_EPS 1e-5f

// ---------- float max-key encoding for atomic max on LDS ----------
__device__ __forceinline__ unsigned enc_f(float f) {
    unsigned u = __float_as_uint(f);
    return (u & 0x80000000u) ? ~u : (u | 0x80000000u);
}
__device__ __forceinline__ float dec_f(unsigned k) {
    unsigned u = (k & 0x80000000u) ? (k & 0x7fffffffu) : ~k;
    return __uint_as_float(u);
}
#define ENC_NEG_INF 0x007FFFFFu   // enc_f(-inf)

__device__ __forceinline__ float lrelu02(float x) { return x > 0.f ? x : 0.2f * x; }

// ======================= K1: omics encoder =======================
// one block per modality o; computes x[(g*256+o)*64 + col] for all g, col
__global__ __launch_bounds__(256) void enc_kernel(
    const float* __restrict__ omics, const float* __restrict__ w,
    const float* __restrict__ b, const float* __restrict__ rot,
    const float* __restrict__ gamma, const float* __restrict__ beta,
    const float* __restrict__ mean, const float* __restrict__ var,
    float* __restrict__ x)
{
    int o = blockIdx.x;
    __shared__ float Wl[D_IN * HDIM];   // 32 KB
    __shared__ float Om[G * D_IN];      // 32 KB
    int t = threadIdx.x;
    for (int i = t; i < D_IN * HDIM; i += 256) Wl[i] = w[o * D_IN * HDIM + i];
    for (int i = t; i < G * D_IN; i += 256) {
        int g = i >> 7, d = i & 127;
        Om[i] = omics[((size_t)g * NNODE + o) * D_IN + d];
    }
    __syncthreads();
    for (int i = 0; i < 16; ++i) {
        int task = t + i * 256;            // 64 g * 64 col
        int g = task >> 6, col = task & 63;
        float acc = b[o * HDIM + col];
        const float* om = &Om[g * D_IN];
        #pragma unroll 8
        for (int d = 0; d < D_IN; ++d) acc = fmaf(om[d], Wl[d * HDIM + col], acc);
        float r = rot[o * HDIM + col];
        float v = acc * (cosf(r) + sinf(r));
        v = fmaxf(v, 0.f);
        v = (v - mean[o * HDIM + col]) * rsqrtf(var[o * HDIM + col] + BN_EPS)
              * gamma[o * HDIM + col] + beta[o * HDIM + col];
        x[((size_t)g * NNODE + o) * HDIM + col] = v;
    }
}

// ======================= K2: GAT1 linear =========================
// h1[n][head][c] = x[n] @ W[:, head*64+c]; also a_src/a_dst logit halves
__global__ __launch_bounds__(256) void gat1_lin(
    const float* __restrict__ x, const float* __restrict__ W,
    const float* __restrict__ att_s, const float* __restrict__ att_d,
    float* __restrict__ h1, float* __restrict__ as1, float* __restrict__ ad1)
{
    int blk = blockIdx.x;                 // 64 nodes per block, 256 blocks
    __shared__ float Xl[64 * 65];         // padded stride 65
    __shared__ float Wl[64 * 256];        // 64 KB
    int t = threadIdx.x;
    int node0 = blk * 64;
    for (int i = t; i < 64 * 64; i += 256) {
        int nl = i >> 6, k = i & 63;
        Xl[nl * 65 + k] = x[(size_t)node0 * HDIM + i];
    }
    for (int i = t; i < 64 * 256; i += 256) Wl[i] = W[i];
    __syncthreads();
    int nl = t >> 2, head = t & 3;
    float out[64];
    #pragma unroll
    for (int c = 0; c < 64; ++c) out[c] = 0.f;
    for (int k = 0; k < 64; ++k) {
        float xv = Xl[nl * 65 + k];
        const float* wr = &Wl[k * 256 + head * 64];
        #pragma unroll
        for (int c = 0; c < 64; ++c) out[c] = fmaf(xv, wr[c], out[c]);
    }
    float asv = 0.f, adv = 0.f;
    #pragma unroll
    for (int c = 0; c < 64; ++c) {
        asv = fmaf(out[c], att_s[head * 64 + c], asv);
        adv = fmaf(out[c], att_d[head * 64 + c], adv);
    }
    int node = node0 + nl;
    float* hrow = &h1[((size_t)node * HEADS + head) * 64];
    #pragma unroll
    for (int c = 0; c < 64; ++c) hrow[c] = out[c];
    as1[node * HEADS + head] = asv;
    ad1[node * HEADS + head] = adv;
}

// ======================= K3: GAT1 edge pass ======================
// grid (G, HEADS); per-graph-per-head softmax + scatter-sum fully in LDS
__global__ __launch_bounds__(256) void gat1_edge(
    const float* __restrict__ h1, const float* __restrict__ as1,
    const float* __restrict__ ad1, const int* __restrict__ eidx,
    const float* __restrict__ bias1, float* __restrict__ x2)
{
    int g = blockIdx.x, head = blockIdx.y;
    __shared__ float hl[NNODE * 64];      // 64 KB
    __shared__ float ol[NNODE * 64];      // 64 KB
    __shared__ float asl[NNODE], adl[NNODE], sl[NNODE], mlf[NNODE];
    int t = threadIdx.x;
    for (int i = t; i < NNODE * 64; i += 256) {
        int node = i >> 6, c = i & 63;
        hl[i] = h1[(((size_t)g * NNODE + node) * HEADS + head) * 64 + c];
        ol[i] = 0.f;
    }
    asl[t] = as1[((size_t)g * NNODE + t) * HEADS + head];
    adl[t] = ad1[((size_t)g * NNODE + t) * HEADS + head];
    sl[t] = 0.f;
    ((unsigned*)mlf)[t] = ENC_NEG_INF;
    __syncthreads();

    const int* srcp = eidx + (size_t)g * E_PER;
    const int* dstp = eidx + E_TOTAL + (size_t)g * E_PER;
    int base = g * NNODE;

    // pass A: segment max
    for (int e = t; e < E_PER; e += 256) {
        int s = srcp[e] - base, d = dstp[e] - base;
        float lg = lrelu02(asl[s] + adl[d]);
        atomicMax((unsigned*)&mlf[d], enc_f(lg));
    }
    __syncthreads();
    {   // decode keys -> float max (0 for nodes with no in-edges)
        unsigned k = ((unsigned*)mlf)[t];
        float mv = (k == ENC_NEG_INF) ? 0.f : dec_f(k);
        __syncthreads();
        mlf[t] = mv;
    }
    __syncthreads();

    // pass B: segment sum of exp
    for (int e = t; e < E_PER; e += 256) {
        int s = srcp[e] - base, d = dstp[e] - base;
        float lg = lrelu02(asl[s] + adl[d]);
        atomicAdd(&sl[d], __expf(lg - mlf[d]));
    }
    __syncthreads();

    // pass C: scatter alpha * h[src]; one wave per edge, one lane per channel
    int wave = t >> 6, lane = t & 63;
    for (int e = wave; e < E_PER; e += 4) {
        int s = srcp[e] - base, d = dstp[e] - base;
        float lg = lrelu02(asl[s] + adl[d]);
        float alpha = __expf(lg - mlf[d]) / (sl[d] + 1e-16f);
        atomicAdd(&ol[d * 64 + lane], alpha * hl[s * 64 + lane]);
    }
    __syncthreads();

    // epilogue: + bias, ELU, write x2
    for (int i = t; i < NNODE * 64; i += 256) {
        int node = i >> 6, c = i & 63;
        float v = ol[i] + bias1[head * 64 + c];
        v = v > 0.f ? v : expm1f(v);
        x2[((size_t)g * NNODE + node) * (HEADS * 64) + head * 64 + c] = v;
    }
}

// ======================= K4: GAT2 linear =========================
__global__ __launch_bounds__(256) void gat2_lin(
    const float* __restrict__ x2, const float* __restrict__ W,
    const float* __restrict__ att_s, const float* __restrict__ att_d,
    float* __restrict__ h2, float* __restrict__ as2, float* __restrict__ ad2)
{
    int blk = blockIdx.x;                 // 64 nodes per block, 256 blocks
    __shared__ float Xl[64 * 257];        // padded
    __shared__ float Wl[256 * 64];        // 64 KB
    int t = threadIdx.x;
    int node0 = blk * 64;
    for (int i = t; i < 64 * 256; i += 256) {
        int nl = i >> 8, k = i & 255;
        Xl[nl * 257 + k] = x2[(size_t)node0 * 256 + i];
    }
    for (int i = t; i < 256 * 64; i += 256) Wl[i] = W[i];
    __syncthreads();
    int nl = t >> 2, q = t & 3;
    float out[16];
    #pragma unroll
    for (int c = 0; c < 16; ++c) out[c] = 0.f;
    for (int k = 0; k < 256; ++k) {
        float xv = Xl[nl * 257 + k];
        const float* wr = &Wl[k * 64 + q * 16];
        #pragma unroll
        for (int c = 0; c < 16; ++c) out[c] = fmaf(xv, wr[c], out[c]);
    }
    float asv = 0.f, adv = 0.f;
    #pragma unroll
    for (int c = 0; c < 16; ++c) {
        asv = fmaf(out[c], att_s[q * 16 + c], asv);
        adv = fmaf(out[c], att_d[q * 16 + c], adv);
    }
    asv += __shfl_xor(asv, 1); asv += __shfl_xor(asv, 2);
    adv += __shfl_xor(adv, 1); adv += __shfl_xor(adv, 2);
    int node = node0 + nl;
    float* hrow = &h2[(size_t)node * 64 + q * 16];
    #pragma unroll
    for (int c = 0; c < 16; ++c) hrow[c] = out[c];
    if (q == 0) { as2[node] = asv; ad2[node] = adv; }
}

// ======================= K5: GAT2 edge + mean-pool ===============
__global__ __launch_bounds__(256) void gat2_edge(
    const float* __restrict__ h2, const float* __restrict__ as2,
    const float* __restrict__ ad2, const int* __restrict__ eidx,
    const float* __restrict__ bias2, float* __restrict__ pooled)
{
    int g = blockIdx.x;
    __shared__ float hl[NNODE * 64];
    __shared__ float ol[NNODE * 64];
    __shared__ float asl[NNODE], adl[NNODE], sl[NNODE], mlf[NNODE];
    __shared__ float pl[4][64];
    int t = threadIdx.x;
    for (int i = t; i < NNODE * 64; i += 256) {
        hl[i] = h2[(size_t)g * NNODE * 64 + i];
        ol[i] = 0.f;
    }
    asl[t] = as2[g * NNODE + t];
    adl[t] = ad2[g * NNODE + t];
    sl[t] = 0.f;
    ((unsigned*)mlf)[t] = ENC_NEG_INF;
    __syncthreads();

    const int* srcp = eidx + (size_t)g * E_PER;
    const int* dstp = eidx + E_TOTAL + (size_t)g * E_PER;
    int base = g * NNODE;

    for (int e = t; e < E_PER; e += 256) {
        int s = srcp[e] - base, d = dstp[e] - base;
        float lg = lrelu02(asl[s] + adl[d]);
        atomicMax((unsigned*)&mlf[d], enc_f(lg));
    }
    __syncthreads();
    {
        unsigned k = ((unsigned*)mlf)[t];
        float mv = (k == ENC_NEG_INF) ? 0.f : dec_f(k);
        __syncthreads();
        mlf[t] = mv;
    }
    __syncthreads();

    for (int e = t; e < E_PER; e += 256) {
        int s = srcp[e] - base, d = dstp[e] - base;
        float lg = lrelu02(asl[s] + adl[d]);
        atomicAdd(&sl[d], __expf(lg - mlf[d]));
    }
    __syncthreads();

    int wave = t >> 6, lane = t & 63;
    for (int e = wave; e < E_PER; e += 4) {
        int s = srcp[e] - base, d = dstp[e] - base;
        float lg = lrelu02(asl[s] + adl[d]);
        float alpha = __expf(lg - mlf[d]) / (sl[d] + 1e-16f);
        atomicAdd(&ol[d * 64 + lane], alpha * hl[s * 64 + lane]);
    }
    __syncthreads();

    // mean pool over the graph's 256 nodes (+ bias2 once: sum(x+b)/N = sum(x)/N + b)
    float p = 0.f;
    for (int node = wave; node < NNODE; node += 4) p += ol[node * 64 + lane];
    pl[wave][lane] = p;
    __syncthreads();
    if (t < 64) {
        float tot = pl[0][t] + pl[1][t] + pl[2][t] + pl[3][t];
        pooled[g * 64 + t] = tot * (1.f / 256.f) + bias2[t];
    }
}

// ======================= K6: classifier ==========================
__global__ __launch_bounds__(64) void cls_kernel(
    const float* __restrict__ pooled, const float* __restrict__ w1,
    const float* __restrict__ b1, const float* __restrict__ w2,
    const float* __restrict__ b2, float* __restrict__ outv)
{
    int g = threadIdx.x;      // 64 threads, one graph each
    float po[64];
    #pragma unroll
    for (int c = 0; c < 64; ++c) po[c] = pooled[g * 64 + c];
    float o = b2[0];
    for (int j = 0; j < 64; ++j) {
        float acc = b1[j];
        #pragma unroll
        for (int c = 0; c < 64; ++c) acc = fmaf(po[c], w1[c * 64 + j], acc);
        acc = fmaxf(acc, 0.f);
        o = fmaf(acc, w2[j], o);
    }
    outv[g] = 1.f / (1.f + __expf(-o));
}

extern "C" void kernel_launch(void* const* d_in, const int* in_sizes, int n_in,
                              void* d_out, int out_size, void* d_ws, size_t ws_size,
                              hipStream_t stream) {
    const float* omics   = (const float*)d_in[0];
    const float* w_omics = (const float*)d_in[1];
    const float* b_omics = (const float*)d_in[2];
    const float* rot     = (const float*)d_in[3];
    const float* bn_g    = (const float*)d_in[4];
    const float* bn_b    = (const float*)d_in[5];
    const float* bn_m    = (const float*)d_in[6];
    const float* bn_v    = (const float*)d_in[7];
    const float* gat1_w  = (const float*)d_in[8];
    const float* att_s1  = (const float*)d_in[9];
    const float* att_d1  = (const float*)d_in[10];
    const float* bias1   = (const float*)d_in[11];
    const float* gat2_w  = (const float*)d_in[12];
    const float* att_s2  = (const float*)d_in[13];
    const float* att_d2  = (const float*)d_in[14];
    const float* bias2   = (const float*)d_in[15];
    const float* cls_w1  = (const float*)d_in[16];
    const float* cls_b1  = (const float*)d_in[17];
    const float* cls_w2  = (const float*)d_in[18];
    const float* cls_b2  = (const float*)d_in[19];
    const int*   eidx    = (const int*)d_in[20];
    // d_in[21] batch_ids unused (layout is known)

    float* ws = (float*)d_ws;
    size_t o_x   = 0;
    size_t o_h1  = o_x  + (size_t)NUM_NODES * HDIM;          // x:  16384*64
    size_t o_as1 = o_h1 + (size_t)NUM_NODES * HEADS * 64;    // h1: 16384*256
    size_t o_ad1 = o_as1 + (size_t)NUM_NODES * HEADS;
    size_t o_x2  = o_ad1 + (size_t)NUM_NODES * HEADS;
    size_t o_h2  = o_x2 + (size_t)NUM_NODES * HEADS * 64;    // x2: 16384*256
    size_t o_as2 = o_h2 + (size_t)NUM_NODES * 64;            // h2: 16384*64
    size_t o_ad2 = o_as2 + (size_t)NUM_NODES;

    float* x   = ws + o_x;
    float* h1  = ws + o_h1;
    float* as1 = ws + o_as1;
    float* ad1 = ws + o_ad1;
    float* x2  = ws + o_x2;
    float* h2  = ws + o_h2;
    float* as2 = ws + o_as2;
    float* ad2 = ws + o_ad2;

    float* outv   = (float*)d_out;        // [64]
    float* pooled = (float*)d_out + G;    // [64*64]

    enc_kernel<<<256, 256, 0, stream>>>(omics, w_omics, b_omics, rot,
                                        bn_g, bn_b, bn_m, bn_v, x);
    gat1_lin<<<256, 256, 0, stream>>>(x, gat1_w, att_s1, att_d1, h1, as1, ad1);
    gat1_edge<<<dim3(G, HEADS), 256, 0, stream>>>(h1, as1, ad1, eidx, bias1, x2);
    gat2_lin<<<256, 256, 0, stream>>>(x2, gat2_w, att_s2, att_d2, h2, as2, ad2);
    gat2_edge<<<G, 256, 0, stream>>>(h2, as2, ad2, eidx, bias2, pooled);
    cls_kernel<<<1, 64, 0, stream>>>(pooled, cls_w1, cls_b1, cls_w2, cls_b2, outv);
}

// Round 2
// 190.767 us; speedup vs baseline: 10.2835x; 10.2835x over previous
//
#include <hip/hip_runtime.h>
#include <hip/hip_bf16.h>
#include <math.h>

#define G 64
#define NNODE 256      // nodes per graph (= O)
#define D_IN 128
#define HDIM 64
#define HEADS 4
#define E_PER 8192
#define NUM_NODES (G * NNODE)
#define E_TOTAL (G * E_PER)
#define BN_EPS 1e-5f

__device__ __forceinline__ float lrelu02(float x) { return x > 0.f ? x : 0.2f * x; }

// ======================= K1: omics encoder =======================
__global__ __launch_bounds__(256) void enc_kernel(
    const float* __restrict__ omics, const float* __restrict__ w,
    const float* __restrict__ b, const float* __restrict__ rot,
    const float* __restrict__ gamma, const float* __restrict__ beta,
    const float* __restrict__ mean, const float* __restrict__ var,
    float* __restrict__ x)
{
    int o = blockIdx.x;
    __shared__ float Wl[D_IN * HDIM];   // 32 KB
    __shared__ float Om[G * D_IN];      // 32 KB
    int t = threadIdx.x;
    for (int i = t; i < D_IN * HDIM; i += 256) Wl[i] = w[o * D_IN * HDIM + i];
    for (int i = t; i < G * D_IN; i += 256) {
        int g = i >> 7, d = i & 127;
        Om[i] = omics[((size_t)g * NNODE + o) * D_IN + d];
    }
    __syncthreads();
    for (int i = 0; i < 16; ++i) {
        int task = t + i * 256;            // 64 g * 64 col
        int g = task >> 6, col = task & 63;
        float acc = b[o * HDIM + col];
        const float* om = &Om[g * D_IN];
        #pragma unroll 8
        for (int d = 0; d < D_IN; ++d) acc = fmaf(om[d], Wl[d * HDIM + col], acc);
        float r = rot[o * HDIM + col];
        float v = acc * (cosf(r) + sinf(r));
        v = fmaxf(v, 0.f);
        v = (v - mean[o * HDIM + col]) * rsqrtf(var[o * HDIM + col] + BN_EPS)
              * gamma[o * HDIM + col] + beta[o * HDIM + col];
        x[((size_t)g * NNODE + o) * HDIM + col] = v;
    }
}

// ======================= K2: GAT1 linear =========================
__global__ __launch_bounds__(256) void gat1_lin(
    const float* __restrict__ x, const float* __restrict__ W,
    const float* __restrict__ att_s, const float* __restrict__ att_d,
    float* __restrict__ h1, float* __restrict__ as1, float* __restrict__ ad1)
{
    int blk = blockIdx.x;
    __shared__ float Xl[64 * 65];
    __shared__ float Wl[64 * 256];
    int t = threadIdx.x;
    int node0 = blk * 64;
    for (int i = t; i < 64 * 64; i += 256) {
        int nl = i >> 6, k = i & 63;
        Xl[nl * 65 + k] = x[(size_t)node0 * HDIM + i];
    }
    for (int i = t; i < 64 * 256; i += 256) Wl[i] = W[i];
    __syncthreads();
    int nl = t >> 2, head = t & 3;
    float out[64];
    #pragma unroll
    for (int c = 0; c < 64; ++c) out[c] = 0.f;
    for (int k = 0; k < 64; ++k) {
        float xv = Xl[nl * 65 + k];
        const float* wr = &Wl[k * 256 + head * 64];
        #pragma unroll
        for (int c = 0; c < 64; ++c) out[c] = fmaf(xv, wr[c], out[c]);
    }
    float asv = 0.f, adv = 0.f;
    #pragma unroll
    for (int c = 0; c < 64; ++c) {
        asv = fmaf(out[c], att_s[head * 64 + c], asv);
        adv = fmaf(out[c], att_d[head * 64 + c], adv);
    }
    int node = node0 + nl;
    float* hrow = &h1[((size_t)node * HEADS + head) * 64];
    #pragma unroll
    for (int c = 0; c < 64; ++c) hrow[c] = out[c];
    as1[node * HEADS + head] = asv;
    ad1[node * HEADS + head] = adv;
}

// ======================= K3: GAT1 edge (CSR-in-LDS gather) =======
// grid (G, HEADS), 512 threads. Builds per-graph CSR in LDS, then
// wave-per-dst gather with lane-per-channel. No edge max pass: uses
// m~[d] = lrelu(maxAS + ad[d]) which cancels in the softmax.
__global__ __launch_bounds__(512) void gat1_edge_csr(
    const float* __restrict__ h1, const float* __restrict__ as1,
    const float* __restrict__ ad1, const int* __restrict__ eidx,
    const float* __restrict__ bias1, float* __restrict__ x2)
{
    int g = blockIdx.x, head = blockIdx.y;
    __shared__ float hl[NNODE * 64];        // 64 KB
    __shared__ unsigned short ssrc[E_PER];  // 16 KB
    __shared__ float anum[E_PER];           // 32 KB
    __shared__ float asl[NNODE], adl[NNODE], mt[NNODE];
    __shared__ int cnt[NNODE], offv[NNODE], cur[NNODE];
    __shared__ float wmax[8];
    __shared__ int wsum[8];
    int t = threadIdx.x;

    for (int i = t; i < NNODE * 16; i += 512) {
        int node = i >> 4, cq = i & 15;
        ((float4*)hl)[node * 16 + cq] =
            ((const float4*)h1)[((size_t)(g * NNODE + node) * HEADS + head) * 16 + cq];
    }
    if (t < NNODE) {
        asl[t] = as1[(g * NNODE + t) * HEADS + head];
        adl[t] = ad1[(g * NNODE + t) * HEADS + head];
        cnt[t] = 0;
    }
    __syncthreads();

    // maxAS over the graph's 256 nodes
    {
        float mv = (t < NNODE) ? asl[t] : -1e30f;
        #pragma unroll
        for (int d = 32; d; d >>= 1) mv = fmaxf(mv, __shfl_xor(mv, d));
        if ((t & 63) == 0) wmax[t >> 6] = mv;
    }
    __syncthreads();
    if (t < NNODE) {
        float M = fmaxf(fmaxf(wmax[0], wmax[1]), fmaxf(wmax[2], wmax[3]));
        mt[t] = lrelu02(M + adl[t]);
    }

    const int* srcp = eidx + (size_t)g * E_PER;
    const int* dstp = eidx + E_TOTAL + (size_t)g * E_PER;
    int base = g * NNODE;

    // histogram of dst
    for (int e = t; e < E_PER; e += 512) atomicAdd(&cnt[dstp[e] - base], 1);
    __syncthreads();

    // exclusive scan of cnt (4 waves of 64 + wave-offset fixup)
    int vincl = (t < NNODE) ? cnt[t] : 0;
    #pragma unroll
    for (int d = 1; d < 64; d <<= 1) {
        int o = __shfl_up(vincl, d);
        if ((t & 63) >= d) vincl += o;
    }
    if (t < NNODE && (t & 63) == 63) wsum[t >> 6] = vincl;
    __syncthreads();
    if (t < NNODE) {
        int w = t >> 6;
        int add = 0;
        if (w > 0) add += wsum[0];
        if (w > 1) add += wsum[1];
        if (w > 2) add += wsum[2];
        int ex = vincl - cnt[t] + add;
        offv[t] = ex; cur[t] = ex;
    }
    __syncthreads();

    // scatter edges sorted by dst; precompute exp numerators
    for (int e = t; e < E_PER; e += 512) {
        int s = srcp[e] - base, d = dstp[e] - base;
        int pos = atomicAdd(&cur[d], 1);
        ssrc[pos] = (unsigned short)s;
        anum[pos] = __expf(lrelu02(asl[s] + adl[d]) - mt[d]);
    }
    __syncthreads();

    // gather: wave per dst, lane per channel
    int w = t >> 6, c = t & 63;
    for (int di = 0; di < 32; ++di) {
        int d = w * 32 + di;
        int rs = offv[d], deg = cnt[d];
        float acc = 0.f, ss = 0.f;
        int k = 0;
        for (; k + 3 < deg; k += 4) {
            int s0 = ssrc[rs + k], s1 = ssrc[rs + k + 1];
            int s2 = ssrc[rs + k + 2], s3 = ssrc[rs + k + 3];
            float a0 = anum[rs + k], a1 = anum[rs + k + 1];
            float a2 = anum[rs + k + 2], a3 = anum[rs + k + 3];
            acc = fmaf(a0, hl[s0 * 64 + c], acc);
            acc = fmaf(a1, hl[s1 * 64 + c], acc);
            acc = fmaf(a2, hl[s2 * 64 + c], acc);
            acc = fmaf(a3, hl[s3 * 64 + c], acc);
            ss += (a0 + a1) + (a2 + a3);
        }
        for (; k < deg; ++k) {
            int s0 = ssrc[rs + k]; float a0 = anum[rs + k];
            acc = fmaf(a0, hl[s0 * 64 + c], acc);
            ss += a0;
        }
        float v = acc / (ss + 1e-16f) + bias1[head * 64 + c];
        v = v > 0.f ? v : expm1f(v);
        x2[(size_t)(base + d) * (HEADS * 64) + head * 64 + c] = v;
    }
}

// ======================= K4: GAT2 linear =========================
__global__ __launch_bounds__(256) void gat2_lin(
    const float* __restrict__ x2, const float* __restrict__ W,
    const float* __restrict__ att_s, const float* __restrict__ att_d,
    float* __restrict__ h2, float* __restrict__ as2, float* __restrict__ ad2)
{
    int blk = blockIdx.x;
    __shared__ float Xl[64 * 257];
    __shared__ float Wl[256 * 64];
    int t = threadIdx.x;
    int node0 = blk * 64;
    for (int i = t; i < 64 * 256; i += 256) {
        int nl = i >> 8, k = i & 255;
        Xl[nl * 257 + k] = x2[(size_t)node0 * 256 + i];
    }
    for (int i = t; i < 256 * 64; i += 256) Wl[i] = W[i];
    __syncthreads();
    int nl = t >> 2, q = t & 3;
    float out[16];
    #pragma unroll
    for (int c = 0; c < 16; ++c) out[c] = 0.f;
    for (int k = 0; k < 256; ++k) {
        float xv = Xl[nl * 257 + k];
        const float* wr = &Wl[k * 64 + q * 16];
        #pragma unroll
        for (int c = 0; c < 16; ++c) out[c] = fmaf(xv, wr[c], out[c]);
    }
    float asv = 0.f, adv = 0.f;
    #pragma unroll
    for (int c = 0; c < 16; ++c) {
        asv = fmaf(out[c], att_s[q * 16 + c], asv);
        adv = fmaf(out[c], att_d[q * 16 + c], adv);
    }
    asv += __shfl_xor(asv, 1); asv += __shfl_xor(asv, 2);
    adv += __shfl_xor(adv, 1); adv += __shfl_xor(adv, 2);
    int node = node0 + nl;
    float* hrow = &h2[(size_t)node * 64 + q * 16];
    #pragma unroll
    for (int c = 0; c < 16; ++c) hrow[c] = out[c];
    if (q == 0) { as2[node] = asv; ad2[node] = adv; }
}

// ======================= K5: GAT2 edge + partial pool ============
// grid (G, 4): each block builds full CSR, gathers its quarter of dst
// rows, accumulates the partial mean-pool sum (output x never stored).
__global__ __launch_bounds__(512) void gat2_edge_csr(
    const float* __restrict__ h2, const float* __restrict__ as2,
    const float* __restrict__ ad2, const int* __restrict__ eidx,
    float* __restrict__ pl4)
{
    int g = blockIdx.x, q = blockIdx.y;
    __shared__ float hl[NNODE * 64];
    __shared__ unsigned short ssrc[E_PER];
    __shared__ float anum[E_PER];
    __shared__ float asl[NNODE], adl[NNODE], mt[NNODE];
    __shared__ int cnt[NNODE], offv[NNODE], cur[NNODE];
    __shared__ float wmax[8];
    __shared__ int wsum[8];
    __shared__ float plq[8][64];
    int t = threadIdx.x;

    for (int i = t; i < NNODE * 16; i += 512)
        ((float4*)hl)[i] = ((const float4*)h2)[(size_t)g * NNODE * 16 + i];
    if (t < NNODE) {
        asl[t] = as2[g * NNODE + t];
        adl[t] = ad2[g * NNODE + t];
        cnt[t] = 0;
    }
    __syncthreads();

    {
        float mv = (t < NNODE) ? asl[t] : -1e30f;
        #pragma unroll
        for (int d = 32; d; d >>= 1) mv = fmaxf(mv, __shfl_xor(mv, d));
        if ((t & 63) == 0) wmax[t >> 6] = mv;
    }
    __syncthreads();
    if (t < NNODE) {
        float M = fmaxf(fmaxf(wmax[0], wmax[1]), fmaxf(wmax[2], wmax[3]));
        mt[t] = lrelu02(M + adl[t]);
    }

    const int* srcp = eidx + (size_t)g * E_PER;
    const int* dstp = eidx + E_TOTAL + (size_t)g * E_PER;
    int base = g * NNODE;

    for (int e = t; e < E_PER; e += 512) atomicAdd(&cnt[dstp[e] - base], 1);
    __syncthreads();

    int vincl = (t < NNODE) ? cnt[t] : 0;
    #pragma unroll
    for (int d = 1; d < 64; d <<= 1) {
        int o = __shfl_up(vincl, d);
        if ((t & 63) >= d) vincl += o;
    }
    if (t < NNODE && (t & 63) == 63) wsum[t >> 6] = vincl;
    __syncthreads();
    if (t < NNODE) {
        int w = t >> 6;
        int add = 0;
        if (w > 0) add += wsum[0];
        if (w > 1) add += wsum[1];
        if (w > 2) add += wsum[2];
        int ex = vincl - cnt[t] + add;
        offv[t] = ex; cur[t] = ex;
    }
    __syncthreads();

    for (int e = t; e < E_PER; e += 512) {
        int s = srcp[e] - base, d = dstp[e] - base;
        int pos = atomicAdd(&cur[d], 1);
        ssrc[pos] = (unsigned short)s;
        anum[pos] = __expf(lrelu02(asl[s] + adl[d]) - mt[d]);
    }
    __syncthreads();

    int w = t >> 6, c = t & 63;
    float psum = 0.f;
    for (int di = 0; di < 8; ++di) {
        int d = q * 64 + w * 8 + di;
        int rs = offv[d], deg = cnt[d];
        float acc = 0.f, ss = 0.f;
        int k = 0;
        for (; k + 3 < deg; k += 4) {
            int s0 = ssrc[rs + k], s1 = ssrc[rs + k + 1];
            int s2 = ssrc[rs + k + 2], s3 = ssrc[rs + k + 3];
            float a0 = anum[rs + k], a1 = anum[rs + k + 1];
            float a2 = anum[rs + k + 2], a3 = anum[rs + k + 3];
            acc = fmaf(a0, hl[s0 * 64 + c], acc);
            acc = fmaf(a1, hl[s1 * 64 + c], acc);
            acc = fmaf(a2, hl[s2 * 64 + c], acc);
            acc = fmaf(a3, hl[s3 * 64 + c], acc);
            ss += (a0 + a1) + (a2 + a3);
        }
        for (; k < deg; ++k) {
            int s0 = ssrc[rs + k]; float a0 = anum[rs + k];
            acc = fmaf(a0, hl[s0 * 64 + c], acc);
            ss += a0;
        }
        psum += acc / (ss + 1e-16f);
    }
    plq[w][c] = psum;
    __syncthreads();
    if (t < 64) {
        float tot = 0.f;
        #pragma unroll
        for (int ww = 0; ww < 8; ++ww) tot += plq[ww][t];
        pl4[(g * 4 + q) * 64 + t] = tot;
    }
}

// ======================= K6: pool-combine + classifier ===========
__global__ __launch_bounds__(64) void cls_kernel(
    const float* __restrict__ pl4, const float* __restrict__ bias2,
    const float* __restrict__ w1, const float* __restrict__ b1,
    const float* __restrict__ w2, const float* __restrict__ b2,
    float* __restrict__ outv, float* __restrict__ pooled)
{
    int g = blockIdx.x, c = threadIdx.x;
    float po = 0.f;
    #pragma unroll
    for (int q = 0; q < 4; ++q) po += pl4[(g * 4 + q) * 64 + c];
    po = po * (1.f / 256.f) + bias2[c];
    pooled[g * 64 + c] = po;
    __shared__ float poL[64];
    poL[c] = po;
    __syncthreads();
    float acc = b1[c];
    for (int k = 0; k < 64; ++k) acc = fmaf(poL[k], w1[k * 64 + c], acc);
    acc = fmaxf(acc, 0.f);
    float contrib = acc * w2[c];
    #pragma unroll
    for (int d = 32; d; d >>= 1) contrib += __shfl_xor(contrib, d);
    if (c == 0) outv[g] = 1.f / (1.f + __expf(-contrib));
}

extern "C" void kernel_launch(void* const* d_in, const int* in_sizes, int n_in,
                              void* d_out, int out_size, void* d_ws, size_t ws_size,
                              hipStream_t stream) {
    const float* omics   = (const float*)d_in[0];
    const float* w_omics = (const float*)d_in[1];
    const float* b_omics = (const float*)d_in[2];
    const float* rot     = (const float*)d_in[3];
    const float* bn_g    = (const float*)d_in[4];
    const float* bn_b    = (const float*)d_in[5];
    const float* bn_m    = (const float*)d_in[6];
    const float* bn_v    = (const float*)d_in[7];
    const float* gat1_w  = (const float*)d_in[8];
    const float* att_s1  = (const float*)d_in[9];
    const float* att_d1  = (const float*)d_in[10];
    const float* bias1   = (const float*)d_in[11];
    const float* gat2_w  = (const float*)d_in[12];
    const float* att_s2  = (const float*)d_in[13];
    const float* att_d2  = (const float*)d_in[14];
    const float* bias2   = (const float*)d_in[15];
    const float* cls_w1  = (const float*)d_in[16];
    const float* cls_b1  = (const float*)d_in[17];
    const float* cls_w2  = (const float*)d_in[18];
    const float* cls_b2  = (const float*)d_in[19];
    const int*   eidx    = (const int*)d_in[20];

    float* ws = (float*)d_ws;
    size_t o_x   = 0;
    size_t o_h1  = o_x  + (size_t)NUM_NODES * HDIM;
    size_t o_as1 = o_h1 + (size_t)NUM_NODES * HEADS * 64;
    size_t o_ad1 = o_as1 + (size_t)NUM_NODES * HEADS;
    size_t o_x2  = o_ad1 + (size_t)NUM_NODES * HEADS;
    size_t o_h2  = o_x2 + (size_t)NUM_NODES * HEADS * 64;
    size_t o_as2 = o_h2 + (size_t)NUM_NODES * 64;
    size_t o_ad2 = o_as2 + (size_t)NUM_NODES;
    size_t o_pl4 = o_ad2 + (size_t)NUM_NODES;

    float* x   = ws + o_x;
    float* h1  = ws + o_h1;
    float* as1 = ws + o_as1;
    float* ad1 = ws + o_ad1;
    float* x2  = ws + o_x2;
    float* h2  = ws + o_h2;
    float* as2 = ws + o_as2;
    float* ad2 = ws + o_ad2;
    float* pl4 = ws + o_pl4;

    float* outv   = (float*)d_out;        // [64]
    float* pooled = (float*)d_out + G;    // [64*64]

    enc_kernel<<<256, 256, 0, stream>>>(omics, w_omics, b_omics, rot,
                                        bn_g, bn_b, bn_m, bn_v, x);
    gat1_lin<<<256, 256, 0, stream>>>(x, gat1_w, att_s1, att_d1, h1, as1, ad1);
    gat1_edge_csr<<<dim3(G, HEADS), 512, 0, stream>>>(h1, as1, ad1, eidx, bias1, x2);
    gat2_lin<<<256, 256, 0, stream>>>(x2, gat2_w, att_s2, att_d2, h2, as2, ad2);
    gat2_edge_csr<<<dim3(G, 4), 512, 0, stream>>>(h2, as2, ad2, eidx, pl4);
    cls_kernel<<<G, 64, 0, stream>>>(pl4, bias2, cls_w1, cls_b1, cls_w2, cls_b2,
                                     outv, pooled);
}

// Round 3
// 123.262 us; speedup vs baseline: 15.9152x; 1.5476x over previous
//
#include <hip/hip_runtime.h>
#include <hip/hip_bf16.h>
#include <math.h>

#define G 64
#define NNODE 256      // nodes per graph (= O)
#define D_IN 128
#define HDIM 64
#define HEADS 4
#define E_PER 8192
#define NUM_NODES (G * NNODE)
#define E_TOTAL (G * E_PER)
#define BN_EPS 1e-5f

__device__ __forceinline__ float lrelu02(float x) { return x > 0.f ? x : 0.2f * x; }

// ======================= K1: omics encoder =======================
// block = modality o. Register tile: thread = 4 graphs x 4 cols.
__global__ __launch_bounds__(256) void enc_kernel(
    const float* __restrict__ omics, const float* __restrict__ w,
    const float* __restrict__ b, const float* __restrict__ rot,
    const float* __restrict__ gamma, const float* __restrict__ beta,
    const float* __restrict__ mean, const float* __restrict__ var,
    float* __restrict__ x)
{
    int o = blockIdx.x;
    __shared__ float Wl[D_IN * HDIM];       // [128][64] 32 KB
    __shared__ float Om[G * 132];           // [64][128] pad->132, 33 KB
    int t = threadIdx.x;
    for (int i = t; i < D_IN * HDIM / 4; i += 256)
        ((float4*)Wl)[i] = ((const float4*)(w + (size_t)o * D_IN * HDIM))[i];
    for (int i = t; i < G * (D_IN / 4); i += 256) {
        int g = i >> 5, dq = i & 31;
        *((float4*)(Om + g * 132) + dq) =
            ((const float4*)(omics + ((size_t)g * NNODE + o) * D_IN))[dq];
    }
    __syncthreads();

    int w4 = t >> 6, l = t & 63;
    int cq = l & 15, gsub = l >> 4;
    int gbase = w4 * 4 + gsub;              // g = gi*16 + gbase
    float4 acc[4];
    #pragma unroll
    for (int gi = 0; gi < 4; ++gi) acc[gi] = make_float4(0.f, 0.f, 0.f, 0.f);

    for (int d = 0; d < D_IN; ++d) {
        float4 wv = *(const float4*)&Wl[d * 64 + cq * 4];
        #pragma unroll
        for (int gi = 0; gi < 4; ++gi) {
            float ov = Om[(gi * 16 + gbase) * 132 + d];
            acc[gi].x = fmaf(ov, wv.x, acc[gi].x);
            acc[gi].y = fmaf(ov, wv.y, acc[gi].y);
            acc[gi].z = fmaf(ov, wv.z, acc[gi].z);
            acc[gi].w = fmaf(ov, wv.w, acc[gi].w);
        }
    }

    // per-column params (independent of g)
    float4 bv = ((const float4*)b)[o * 16 + cq];
    float4 rv = ((const float4*)rot)[o * 16 + cq];
    float4 mv = ((const float4*)mean)[o * 16 + cq];
    float4 vv = ((const float4*)var)[o * 16 + cq];
    float4 gv = ((const float4*)gamma)[o * 16 + cq];
    float4 be = ((const float4*)beta)[o * 16 + cq];
    float4 sc, kk;
    sc.x = cosf(rv.x) + sinf(rv.x); sc.y = cosf(rv.y) + sinf(rv.y);
    sc.z = cosf(rv.z) + sinf(rv.z); sc.w = cosf(rv.w) + sinf(rv.w);
    kk.x = gv.x * rsqrtf(vv.x + BN_EPS); kk.y = gv.y * rsqrtf(vv.y + BN_EPS);
    kk.z = gv.z * rsqrtf(vv.z + BN_EPS); kk.w = gv.w * rsqrtf(vv.w + BN_EPS);

    #pragma unroll
    for (int gi = 0; gi < 4; ++gi) {
        int g = gi * 16 + gbase;
        float4 v;
        v.x = fmaxf((acc[gi].x + bv.x) * sc.x, 0.f);
        v.y = fmaxf((acc[gi].y + bv.y) * sc.y, 0.f);
        v.z = fmaxf((acc[gi].z + bv.z) * sc.z, 0.f);
        v.w = fmaxf((acc[gi].w + bv.w) * sc.w, 0.f);
        v.x = (v.x - mv.x) * kk.x + be.x;
        v.y = (v.y - mv.y) * kk.y + be.y;
        v.z = (v.z - mv.z) * kk.z + be.z;
        v.w = (v.w - mv.w) * kk.w + be.w;
        *(float4*)&x[((size_t)(g * NNODE + o)) * 64 + cq * 4] = v;
    }
}

// ======================= K2: GAT1 linear =========================
// block = 64 nodes; wave = head; thread = 4 nodes x 16 cols.
__global__ __launch_bounds__(256) void gat1_lin(
    const float* __restrict__ x, const float* __restrict__ W,
    const float* __restrict__ att_s, const float* __restrict__ att_d,
    float* __restrict__ h1, float* __restrict__ as1, float* __restrict__ ad1)
{
    int blk = blockIdx.x;
    __shared__ float Xl[64 * 65];
    __shared__ float Wl[64 * 256];          // 64 KB
    int t = threadIdx.x;
    int node0 = blk * 64;
    for (int i = t; i < 64 * 64; i += 256) {
        int nl = i >> 6, k = i & 63;
        Xl[nl * 65 + k] = x[(size_t)node0 * HDIM + i];
    }
    for (int i = t; i < 64 * 256 / 4; i += 256)
        ((float4*)Wl)[i] = ((const float4*)W)[i];
    __syncthreads();

    int w = t >> 6, l = t & 63;             // w = head
    int nsub = l >> 2, csel = l & 3;        // node n = ni*16+nsub, col c = cj*16+csel*4
    float4 acc[4][4];
    #pragma unroll
    for (int ni = 0; ni < 4; ++ni)
        #pragma unroll
        for (int cj = 0; cj < 4; ++cj) acc[ni][cj] = make_float4(0.f, 0.f, 0.f, 0.f);

    for (int k = 0; k < 64; ++k) {
        float4 wv[4];
        #pragma unroll
        for (int cj = 0; cj < 4; ++cj)
            wv[cj] = *(const float4*)&Wl[k * 256 + w * 64 + cj * 16 + csel * 4];
        #pragma unroll
        for (int ni = 0; ni < 4; ++ni) {
            float xv = Xl[(ni * 16 + nsub) * 65 + k];
            #pragma unroll
            for (int cj = 0; cj < 4; ++cj) {
                acc[ni][cj].x = fmaf(xv, wv[cj].x, acc[ni][cj].x);
                acc[ni][cj].y = fmaf(xv, wv[cj].y, acc[ni][cj].y);
                acc[ni][cj].z = fmaf(xv, wv[cj].z, acc[ni][cj].z);
                acc[ni][cj].w = fmaf(xv, wv[cj].w, acc[ni][cj].w);
            }
        }
    }

    float4 as_w[4], ad_w[4];
    #pragma unroll
    for (int cj = 0; cj < 4; ++cj) {
        as_w[cj] = ((const float4*)att_s)[w * 16 + cj * 4 + csel];
        ad_w[cj] = ((const float4*)att_d)[w * 16 + cj * 4 + csel];
    }
    #pragma unroll
    for (int ni = 0; ni < 4; ++ni) {
        int n = ni * 16 + nsub;
        float asv = 0.f, adv = 0.f;
        #pragma unroll
        for (int cj = 0; cj < 4; ++cj) {
            asv += acc[ni][cj].x * as_w[cj].x + acc[ni][cj].y * as_w[cj].y
                 + acc[ni][cj].z * as_w[cj].z + acc[ni][cj].w * as_w[cj].w;
            adv += acc[ni][cj].x * ad_w[cj].x + acc[ni][cj].y * ad_w[cj].y
                 + acc[ni][cj].z * ad_w[cj].z + acc[ni][cj].w * ad_w[cj].w;
            *(float4*)&h1[((size_t)(node0 + n) * HEADS + w) * 64 + cj * 16 + csel * 4]
                = acc[ni][cj];
        }
        asv += __shfl_xor(asv, 1); asv += __shfl_xor(asv, 2);
        adv += __shfl_xor(adv, 1); adv += __shfl_xor(adv, 2);
        if (csel == 0) {
            as1[(node0 + n) * HEADS + w] = asv;
            ad1[(node0 + n) * HEADS + w] = adv;
        }
    }
}

// ======================= K3: GAT1 edge (CSR + quad-edge gather) ==
__global__ __launch_bounds__(512) void gat1_edge_csr(
    const float* __restrict__ h1, const float* __restrict__ as1,
    const float* __restrict__ ad1, const int* __restrict__ eidx,
    const float* __restrict__ bias1, float* __restrict__ x2)
{
    int g = blockIdx.x, head = blockIdx.y;
    __shared__ float hl[NNODE * 64];                 // 64 KB
    __shared__ unsigned long long earr[E_PER];       // 64 KB packed (anum,src)
    __shared__ float asl[NNODE], adl[NNODE], mt[NNODE];
    __shared__ int cnt[NNODE], offv[NNODE], cur[NNODE];
    __shared__ float wmax[8];
    __shared__ int wsum[8];
    int t = threadIdx.x;

    for (int i = t; i < NNODE * 16; i += 512) {
        int node = i >> 4, cq2 = i & 15;
        ((float4*)hl)[node * 16 + cq2] =
            ((const float4*)h1)[((size_t)(g * NNODE + node) * HEADS + head) * 16 + cq2];
    }
    if (t < NNODE) {
        asl[t] = as1[(g * NNODE + t) * HEADS + head];
        adl[t] = ad1[(g * NNODE + t) * HEADS + head];
        cnt[t] = 0;
    }
    __syncthreads();

    {   // maxAS over 256 nodes
        float mv = (t < NNODE) ? asl[t] : -1e30f;
        #pragma unroll
        for (int d = 32; d; d >>= 1) mv = fmaxf(mv, __shfl_xor(mv, d));
        if ((t & 63) == 0) wmax[t >> 6] = mv;
    }
    __syncthreads();
    if (t < NNODE) {
        float M = fmaxf(fmaxf(wmax[0], wmax[1]), fmaxf(wmax[2], wmax[3]));
        mt[t] = lrelu02(M + adl[t]);
    }

    const int* srcp = eidx + (size_t)g * E_PER;
    const int* dstp = eidx + E_TOTAL + (size_t)g * E_PER;
    int base = g * NNODE;

    for (int e = t; e < E_PER; e += 512) atomicAdd(&cnt[dstp[e] - base], 1);
    __syncthreads();

    int vincl = (t < NNODE) ? cnt[t] : 0;
    #pragma unroll
    for (int d = 1; d < 64; d <<= 1) {
        int o = __shfl_up(vincl, d);
        if ((t & 63) >= d) vincl += o;
    }
    if (t < NNODE && (t & 63) == 63) wsum[t >> 6] = vincl;
    __syncthreads();
    if (t < NNODE) {
        int w = t >> 6;
        int add = 0;
        if (w > 0) add += wsum[0];
        if (w > 1) add += wsum[1];
        if (w > 2) add += wsum[2];
        int ex = vincl - cnt[t] + add;
        offv[t] = ex; cur[t] = ex;
    }
    __syncthreads();

    for (int e = t; e < E_PER; e += 512) {
        int s = srcp[e] - base, d = dstp[e] - base;
        int pos = atomicAdd(&cur[d], 1);
        float a = __expf(lrelu02(asl[s] + adl[d]) - mt[d]);
        earr[pos] = ((unsigned long long)__float_as_uint(a) << 32) | (unsigned)s;
    }
    __syncthreads();

    // gather: wave per dst; lane = (edge-slot sub, channel-quad cq)
    int w = t >> 6, l = t & 63;
    int sub = l >> 4, cq = l & 15;
    float4 bj = ((const float4*)bias1)[head * 16 + cq];
    for (int di = 0; di < 32; ++di) {
        int d = w * 32 + di;
        int rs = offv[d], deg = cnt[d];
        float4 acc = make_float4(0.f, 0.f, 0.f, 0.f);
        float ss = 0.f;
        for (int k = 0; k < deg; k += 4) {
            int e = k + sub;
            int idx = rs + (e < deg ? e : deg - 1);
            unsigned long long p = earr[idx];
            float a = (e < deg) ? __uint_as_float((unsigned)(p >> 32)) : 0.f;
            int s = (int)(p & 0xffffu);
            float4 hv = *(const float4*)&hl[s * 64 + cq * 4];
            acc.x = fmaf(a, hv.x, acc.x);
            acc.y = fmaf(a, hv.y, acc.y);
            acc.z = fmaf(a, hv.z, acc.z);
            acc.w = fmaf(a, hv.w, acc.w);
            ss += a;
        }
        #pragma unroll
        for (int m = 16; m <= 32; m <<= 1) {
            acc.x += __shfl_xor(acc.x, m);
            acc.y += __shfl_xor(acc.y, m);
            acc.z += __shfl_xor(acc.z, m);
            acc.w += __shfl_xor(acc.w, m);
            ss    += __shfl_xor(ss, m);
        }
        if (sub == 0) {
            float inv = 1.f / (ss + 1e-16f);
            float4 v;
            v.x = acc.x * inv + bj.x; v.y = acc.y * inv + bj.y;
            v.z = acc.z * inv + bj.z; v.w = acc.w * inv + bj.w;
            v.x = v.x > 0.f ? v.x : expm1f(v.x);
            v.y = v.y > 0.f ? v.y : expm1f(v.y);
            v.z = v.z > 0.f ? v.z : expm1f(v.z);
            v.w = v.w > 0.f ? v.w : expm1f(v.w);
            *(float4*)&x2[(size_t)(base + d) * 256 + head * 64 + cq * 4] = v;
        }
    }
}

// ======================= K4: GAT2 linear =========================
// block = 64 nodes; thread = 4 nodes x 4 cols, k vectorized by 4.
__global__ __launch_bounds__(256) void gat2_lin(
    const float* __restrict__ x2, const float* __restrict__ W,
    const float* __restrict__ att_s, const float* __restrict__ att_d,
    float* __restrict__ h2, float* __restrict__ as2, float* __restrict__ ad2)
{
    int blk = blockIdx.x;
    __shared__ float Xl[64 * 260];          // pad 256->260, 66.6 KB
    __shared__ float Wl[256 * 64];          // 64 KB
    int t = threadIdx.x;
    int node0 = blk * 64;
    for (int i = t; i < 64 * 64; i += 256) {
        int nl = i >> 6, kq = i & 63;
        *((float4*)(Xl + nl * 260) + kq) =
            ((const float4*)(x2 + (size_t)(node0 + nl) * 256))[kq];
    }
    for (int i = t; i < 256 * 64 / 4; i += 256)
        ((float4*)Wl)[i] = ((const float4*)W)[i];
    __syncthreads();

    int w = t >> 6, l = t & 63;
    int cq = l & 15, nsub = l >> 4;         // node n = w*16 + ni*4 + nsub
    float4 acc[4];
    #pragma unroll
    for (int ni = 0; ni < 4; ++ni) acc[ni] = make_float4(0.f, 0.f, 0.f, 0.f);

    for (int k0 = 0; k0 < 256; k0 += 4) {
        float4 wv[4];
        #pragma unroll
        for (int kk = 0; kk < 4; ++kk)
            wv[kk] = *(const float4*)&Wl[(k0 + kk) * 64 + cq * 4];
        #pragma unroll
        for (int ni = 0; ni < 4; ++ni) {
            float4 xq = *(const float4*)&Xl[(w * 16 + ni * 4 + nsub) * 260 + k0];
            acc[ni].x = fmaf(xq.x, wv[0].x, acc[ni].x);
            acc[ni].y = fmaf(xq.x, wv[0].y, acc[ni].y);
            acc[ni].z = fmaf(xq.x, wv[0].z, acc[ni].z);
            acc[ni].w = fmaf(xq.x, wv[0].w, acc[ni].w);
            acc[ni].x = fmaf(xq.y, wv[1].x, acc[ni].x);
            acc[ni].y = fmaf(xq.y, wv[1].y, acc[ni].y);
            acc[ni].z = fmaf(xq.y, wv[1].z, acc[ni].z);
            acc[ni].w = fmaf(xq.y, wv[1].w, acc[ni].w);
            acc[ni].x = fmaf(xq.z, wv[2].x, acc[ni].x);
            acc[ni].y = fmaf(xq.z, wv[2].y, acc[ni].y);
            acc[ni].z = fmaf(xq.z, wv[2].z, acc[ni].z);
            acc[ni].w = fmaf(xq.z, wv[2].w, acc[ni].w);
            acc[ni].x = fmaf(xq.w, wv[3].x, acc[ni].x);
            acc[ni].y = fmaf(xq.w, wv[3].y, acc[ni].y);
            acc[ni].z = fmaf(xq.w, wv[3].z, acc[ni].z);
            acc[ni].w = fmaf(xq.w, wv[3].w, acc[ni].w);
        }
    }

    float4 as_w = ((const float4*)att_s)[cq];
    float4 ad_w = ((const float4*)att_d)[cq];
    #pragma unroll
    for (int ni = 0; ni < 4; ++ni) {
        int n = w * 16 + ni * 4 + nsub;
        float asv = acc[ni].x * as_w.x + acc[ni].y * as_w.y
                  + acc[ni].z * as_w.z + acc[ni].w * as_w.w;
        float adv = acc[ni].x * ad_w.x + acc[ni].y * ad_w.y
                  + acc[ni].z * ad_w.z + acc[ni].w * ad_w.w;
        #pragma unroll
        for (int m = 1; m <= 8; m <<= 1) {
            asv += __shfl_xor(asv, m);
            adv += __shfl_xor(adv, m);
        }
        *(float4*)&h2[(size_t)(node0 + n) * 64 + cq * 4] = acc[ni];
        if (cq == 0) { as2[node0 + n] = asv; ad2[node0 + n] = adv; }
    }
}

// ======================= K5: GAT2 edge + partial pool ============
__global__ __launch_bounds__(512) void gat2_edge_csr(
    const float* __restrict__ h2, const float* __restrict__ as2,
    const float* __restrict__ ad2, const int* __restrict__ eidx,
    float* __restrict__ pl4)
{
    int g = blockIdx.x, q = blockIdx.y;
    __shared__ float hl[NNODE * 64];
    __shared__ unsigned long long earr[E_PER];
    __shared__ float asl[NNODE], adl[NNODE], mt[NNODE];
    __shared__ int cnt[NNODE], offv[NNODE], cur[NNODE];
    __shared__ float wmax[8];
    __shared__ int wsum[8];
    __shared__ float plq[8][64];
    int t = threadIdx.x;

    for (int i = t; i < NNODE * 16; i += 512)
        ((float4*)hl)[i] = ((const float4*)h2)[(size_t)g * NNODE * 16 + i];
    if (t < NNODE) {
        asl[t] = as2[g * NNODE + t];
        adl[t] = ad2[g * NNODE + t];
        cnt[t] = 0;
    }
    __syncthreads();

    {
        float mv = (t < NNODE) ? asl[t] : -1e30f;
        #pragma unroll
        for (int d = 32; d; d >>= 1) mv = fmaxf(mv, __shfl_xor(mv, d));
        if ((t & 63) == 0) wmax[t >> 6] = mv;
    }
    __syncthreads();
    if (t < NNODE) {
        float M = fmaxf(fmaxf(wmax[0], wmax[1]), fmaxf(wmax[2], wmax[3]));
        mt[t] = lrelu02(M + adl[t]);
    }

    const int* srcp = eidx + (size_t)g * E_PER;
    const int* dstp = eidx + E_TOTAL + (size_t)g * E_PER;
    int base = g * NNODE;

    for (int e = t; e < E_PER; e += 512) atomicAdd(&cnt[dstp[e] - base], 1);
    __syncthreads();

    int vincl = (t < NNODE) ? cnt[t] : 0;
    #pragma unroll
    for (int d = 1; d < 64; d <<= 1) {
        int o = __shfl_up(vincl, d);
        if ((t & 63) >= d) vincl += o;
    }
    if (t < NNODE && (t & 63) == 63) wsum[t >> 6] = vincl;
    __syncthreads();
    if (t < NNODE) {
        int w = t >> 6;
        int add = 0;
        if (w > 0) add += wsum[0];
        if (w > 1) add += wsum[1];
        if (w > 2) add += wsum[2];
        int ex = vincl - cnt[t] + add;
        offv[t] = ex; cur[t] = ex;
    }
    __syncthreads();

    for (int e = t; e < E_PER; e += 512) {
        int s = srcp[e] - base, d = dstp[e] - base;
        int pos = atomicAdd(&cur[d], 1);
        float a = __expf(lrelu02(asl[s] + adl[d]) - mt[d]);
        earr[pos] = ((unsigned long long)__float_as_uint(a) << 32) | (unsigned)s;
    }
    __syncthreads();

    int w = t >> 6, l = t & 63;
    int sub = l >> 4, cq = l & 15;
    float4 psum = make_float4(0.f, 0.f, 0.f, 0.f);
    for (int di = 0; di < 8; ++di) {
        int d = q * 64 + w * 8 + di;
        int rs = offv[d], deg = cnt[d];
        float4 acc = make_float4(0.f, 0.f, 0.f, 0.f);
        float ss = 0.f;
        for (int k = 0; k < deg; k += 4) {
            int e = k + sub;
            int idx = rs + (e < deg ? e : deg - 1);
            unsigned long long p = earr[idx];
            float a = (e < deg) ? __uint_as_float((unsigned)(p >> 32)) : 0.f;
            int s = (int)(p & 0xffffu);
            float4 hv = *(const float4*)&hl[s * 64 + cq * 4];
            acc.x = fmaf(a, hv.x, acc.x);
            acc.y = fmaf(a, hv.y, acc.y);
            acc.z = fmaf(a, hv.z, acc.z);
            acc.w = fmaf(a, hv.w, acc.w);
            ss += a;
        }
        #pragma unroll
        for (int m = 16; m <= 32; m <<= 1) {
            acc.x += __shfl_xor(acc.x, m);
            acc.y += __shfl_xor(acc.y, m);
            acc.z += __shfl_xor(acc.z, m);
            acc.w += __shfl_xor(acc.w, m);
            ss    += __shfl_xor(ss, m);
        }
        float inv = 1.f / (ss + 1e-16f);
        psum.x = fmaf(acc.x, inv, psum.x);
        psum.y = fmaf(acc.y, inv, psum.y);
        psum.z = fmaf(acc.z, inv, psum.z);
        psum.w = fmaf(acc.w, inv, psum.w);
    }
    if (sub == 0) *(float4*)&plq[w][cq * 4] = psum;
    __syncthreads();
    if (t < 64) {
        float tot = 0.f;
        #pragma unroll
        for (int ww = 0; ww < 8; ++ww) tot += plq[ww][t];
        pl4[(g * 4 + q) * 64 + t] = tot;
    }
}

// ======================= K6: pool-combine + classifier ===========
__global__ __launch_bounds__(64) void cls_kernel(
    const float* __restrict__ pl4, const float* __restrict__ bias2,
    const float* __restrict__ w1, const float* __restrict__ b1,
    const float* __restrict__ w2, const float* __restrict__ b2,
    float* __restrict__ outv, float* __restrict__ pooled)
{
    int g = blockIdx.x, c = threadIdx.x;
    float po = 0.f;
    #pragma unroll
    for (int q = 0; q < 4; ++q) po += pl4[(g * 4 + q) * 64 + c];
    po = po * (1.f / 256.f) + bias2[c];
    pooled[g * 64 + c] = po;
    __shared__ float poL[64];
    poL[c] = po;
    __syncthreads();
    float acc = b1[c];
    for (int k = 0; k < 64; ++k) acc = fmaf(poL[k], w1[k * 64 + c], acc);
    acc = fmaxf(acc, 0.f);
    float contrib = acc * w2[c];
    #pragma unroll
    for (int d = 32; d; d >>= 1) contrib += __shfl_xor(contrib, d);
    if (c == 0) outv[g] = 1.f / (1.f + __expf(-contrib));
}

extern "C" void kernel_launch(void* const* d_in, const int* in_sizes, int n_in,
                              void* d_out, int out_size, void* d_ws, size_t ws_size,
                              hipStream_t stream) {
    const float* omics   = (const float*)d_in[0];
    const float* w_omics = (const float*)d_in[1];
    const float* b_omics = (const float*)d_in[2];
    const float* rot     = (const float*)d_in[3];
    const float* bn_g    = (const float*)d_in[4];
    const float* bn_b    = (const float*)d_in[5];
    const float* bn_m    = (const float*)d_in[6];
    const float* bn_v    = (const float*)d_in[7];
    const float* gat1_w  = (const float*)d_in[8];
    const float* att_s1  = (const float*)d_in[9];
    const float* att_d1  = (const float*)d_in[10];
    const float* bias1   = (const float*)d_in[11];
    const float* gat2_w  = (const float*)d_in[12];
    const float* att_s2  = (const float*)d_in[13];
    const float* att_d2  = (const float*)d_in[14];
    const float* bias2   = (const float*)d_in[15];
    const float* cls_w1  = (const float*)d_in[16];
    const float* cls_b1  = (const float*)d_in[17];
    const float* cls_w2  = (const float*)d_in[18];
    const float* cls_b2  = (const float*)d_in[19];
    const int*   eidx    = (const int*)d_in[20];

    float* ws = (float*)d_ws;
    size_t o_x   = 0;
    size_t o_h1  = o_x  + (size_t)NUM_NODES * HDIM;
    size_t o_as1 = o_h1 + (size_t)NUM_NODES * HEADS * 64;
    size_t o_ad1 = o_as1 + (size_t)NUM_NODES * HEADS;
    size_t o_x2  = o_ad1 + (size_t)NUM_NODES * HEADS;
    size_t o_h2  = o_x2 + (size_t)NUM_NODES * HEADS * 64;
    size_t o_as2 = o_h2 + (size_t)NUM_NODES * 64;
    size_t o_ad2 = o_as2 + (size_t)NUM_NODES;
    size_t o_pl4 = o_ad2 + (size_t)NUM_NODES;

    float* x   = ws + o_x;
    float* h1  = ws + o_h1;
    float* as1 = ws + o_as1;
    float* ad1 = ws + o_ad1;
    float* x2  = ws + o_x2;
    float* h2  = ws + o_h2;
    float* as2 = ws + o_as2;
    float* ad2 = ws + o_ad2;
    float* pl4 = ws + o_pl4;

    float* outv   = (float*)d_out;        // [64]
    float* pooled = (float*)d_out + G;    // [64*64]

    enc_kernel<<<256, 256, 0, stream>>>(omics, w_omics, b_omics, rot,
                                        bn_g, bn_b, bn_m, bn_v, x);
    gat1_lin<<<256, 256, 0, stream>>>(x, gat1_w, att_s1, att_d1, h1, as1, ad1);
    gat1_edge_csr<<<dim3(G, HEADS), 512, 0, stream>>>(h1, as1, ad1, eidx, bias1, x2);
    gat2_lin<<<256, 256, 0, stream>>>(x2, gat2_w, att_s2, att_d2, h2, as2, ad2);
    gat2_edge_csr<<<dim3(G, 4), 512, 0, stream>>>(h2, as2, ad2, eidx, pl4);
    cls_kernel<<<G, 64, 0, stream>>>(pl4, bias2, cls_w1, cls_b1, cls_w2, cls_b2,
                                     outv, pooled);
}